// Round 10
// baseline (3414.376 us; speedup 1.0000x reference)
//
#include <hip/hip_runtime.h>

typedef unsigned short u16;
typedef unsigned long long u64;
typedef short v8s __attribute__((ext_vector_type(8)));
typedef float v4f __attribute__((ext_vector_type(4)));
typedef unsigned v2u __attribute__((ext_vector_type(2)));
typedef unsigned v4u __attribute__((ext_vector_type(4)));

#define Bb 256
#define Tt 512
#define Dd 64
#define Hh 512
#define G4 2048

#define NGROUP 16    // batch groups (16 batch each)
#define NCHUNK 16    // hidden chunks per group (32 hidden units each)
#define BT 16
#define HC 32
#define NCOL 128     // local gate cols = 4 gates * HC

#define WHH_S 520   // 512 + 8 pad (bf16 elems)
#define WIH_S 72    // 64 + 8 pad
#define SMEM_BYTES (NCOL*WHH_S*2 + NCOL*WIH_S*2)   // 151552 -> 1 block/CU

#define MFMA(a,b,c) __builtin_amdgcn_mfma_f32_16x16x32_bf16((a),(b),(c),0,0,0)

#define SENT 0xFFFFFFFFu   // bf16 -NaN pair; impossible for |h|<1

__device__ __forceinline__ u16 f2bf(float f) {
  unsigned u = __float_as_uint(f);
  unsigned r = (u + 0x7fffu + ((u >> 16) & 1u)) >> 16;
  return (u16)r;
}
__device__ __forceinline__ float bf2f(u16 v) {
  return __uint_as_float(((unsigned)v) << 16);
}
__device__ __forceinline__ float sigm(float x) { return 1.0f / (1.0f + __expf(-x)); }
__device__ __forceinline__ float tanh_f(float x) {
  float a = fabsf(x);
  float e = __expf(-2.0f * a);
  float r = (1.0f - e) / (1.0f + e);
  return copysignf(r, x);
}
__device__ __forceinline__ float softplus_f(float x) { return log1pf(__expf(x)); }

// ---------------------------------------------------------------- prep:
// x fp32 [B][T][D] -> bf16 [T][B][D]; sentinel-fill 4 h ring slots + xcd
// handshake table.
__global__ void k_prep(const float* __restrict__ x, u16* __restrict__ x_bf,
                       u16* __restrict__ h_buf)
{
  int stride = gridDim.x * blockDim.x;
  int gid = blockIdx.x * blockDim.x + threadIdx.x;

  // sentinel-fill 4 slots of h ring (1 MB) + xcd table (1 KB)
  const int NS = (4 * Bb * Hh * 2 + 256 * 4) / 16;   // uint4 stores
  for (int i = gid; i < NS; i += stride)
    ((uint4*)h_buf)[i] = make_uint4(~0u, ~0u, ~0u, ~0u);

  const int N4 = Tt * Bb * Dd / 4;
  for (int i = gid; i < N4; i += stride) {
    int idx = i * 4;
    int t = idx >> 14;          // / (B*D)
    int rem = idx & 16383;
    int b = rem >> 6;
    int d = rem & 63;
    float4 v = *(const float4*)(x + (size_t)b * (Tt * Dd) + t * Dd + d);
    unsigned lo = (unsigned)f2bf(v.x) | ((unsigned)f2bf(v.y) << 16);
    unsigned hi = (unsigned)f2bf(v.z) | ((unsigned)f2bf(v.w) << 16);
    *(uint2*)(x_bf + idx) = make_uint2(lo, hi);
  }
}

// ---------------------------------------------------------------- main:
// persistent LSTM. 256 blocks x 64 thr (ONE wave = one fully independent
// agent per chunk), static group/chunk. ZERO barriers in the step loop.
//
// HW facts (passing runs): (a) sc0 stores commit to the shared XCD L2 and
// stay there (R12/R16 WRITE~1MB); (b) sc0sc1 loads always observe
// committed data (R10/R14/R16); (c) depth-4 sentinel ring turns commit
// skew into cheap retries; (d) atomics = die-level coherence point
// (R14); (e) plain stores / inv+plain loads unreliable (R15) -- banned.
// R16 (sc0-store + sc0sc1-load sentinel protocol) = 2064us, best.
// R17 (flag gate) neutral -> poll BW is NOT the dominant term.
//
// R18 levers (kept): 1 wave/block (agents 32->16: max-of-N skew and poll
// traffic halved; MFMA/wave doubles -- free at 5% util); first-probe RTT
// hidden under the x-projection via vmcnt(16) (stores+loads retire
// in-order in vmcnt, so vmcnt(16) retires prior stores + the 2 x loads).
//
// R19 FIX (R18 absmax 0.67): the second x load's asm offset is BYTES --
// R16's `xb + ks*32` was u16 ELEMENTS (=64B). offset:32 read k=16..23
// instead of 32..39. One-line fix: offset:64.
template<bool FAST>
__device__ __forceinline__ void run_steps(
    const u16* const* WhP, const u16* const* WxP,
    const float (*bs)[4], const u16* __restrict__ x_bf,
    u16* __restrict__ h_buf, int bat, int j0, int q, int ko)
{
  float cc[2][4] = {{0.f,0.f,0.f,0.f},{0.f,0.f,0.f,0.f}};

  for (int t = 0; t < Tt; ++t) {
    v4f ac[8];
    #pragma unroll
    for (int i = 0; i < 8; ++i) ac[i] = v4f{0.f,0.f,0.f,0.f};

    const u16* xb = x_bf + (size_t)t * (Bb * Dd) + bat * Dd + ko;
    const u16* hb = h_buf + (size_t)(t & 3) * (Bb * Hh) + bat * Hh + ko;

    v4u xv0, xv1;
    v4u buf[16];
    unsigned done = 0;

    // ---- issue x loads FIRST (oldest), then the 16 h probes; vmcnt(16)
    // retires exactly {prior stores + the 2 x loads} (in-order vmcnt),
    // so the x-projection MFMAs run while the h probes are in flight.
    asm volatile("global_load_dwordx4 %0, %1, off"
                 : "=v"(xv0) : "v"(xb));
    asm volatile("global_load_dwordx4 %0, %1, off offset:64"
                 : "=v"(xv1) : "v"(xb));
    if (t > 0) {
      #pragma unroll
      for (int c = 0; c < 16; ++c)
        asm volatile("global_load_dwordx4 %0, %1, off offset:%c2 sc0 sc1"
                     : "=v"(buf[c]) : "v"(hb), "i"(c * 64));
      asm volatile("s_waitcnt vmcnt(16)");
    } else {
      asm volatile("s_waitcnt vmcnt(0)");
    }
    asm volatile("" : "+v"(xv0));            // R9: pin after drain
    asm volatile("" : "+v"(xv1));
    {
      v8s xf0 = __builtin_bit_cast(v8s, xv0);
      v8s xf1 = __builtin_bit_cast(v8s, xv1);
      #pragma unroll
      for (int i = 0; i < 8; ++i)
        ac[i] = MFMA(*(const v8s*)(WxP[i]), xf0, ac[i]);
      #pragma unroll
      for (int i = 0; i < 8; ++i)
        ac[i] = MFMA(*(const v8s*)(WxP[i] + 32), xf1, ac[i]);
    }

    if (t > 0) {
      // ---- event-driven sentinel consume (R16 protocol, verbatim):
      // first iteration's loads are already in flight.
      bool first = true;
      do {
        if (!first) {
          #pragma unroll
          for (int c = 0; c < 16; ++c)
            if (!(done & (1u << c)))
              asm volatile("global_load_dwordx4 %0, %1, off offset:%c2 sc0 sc1"
                           : "=v"(buf[c]) : "v"(hb), "i"(c * 64));
        }
        first = false;
        asm volatile("s_waitcnt vmcnt(0)");
        unsigned ready = 0;
        #pragma unroll
        for (int c = 0; c < 16; ++c)
          if (!(done & (1u << c))) {
            asm volatile("" : "+v"(buf[c]));   // R9: pin after drain
            unsigned m0 = buf[c][0] > buf[c][1] ? buf[c][0] : buf[c][1];
            unsigned m1 = buf[c][2] > buf[c][3] ? buf[c][2] : buf[c][3];
            unsigned mx = m0 > m1 ? m0 : m1;
            int ok = (mx != SENT);             // any sentinel dword -> SENT
            if (__all(ok)) ready |= (1u << c);
          }
        #pragma unroll
        for (int c = 0; c < 16; ++c)
          if (ready & (1u << c)) {
            v8s hf = __builtin_bit_cast(v8s, buf[c]);
            #pragma unroll
            for (int i = 0; i < 8; ++i)
              ac[i] = MFMA(*(const v8s*)(WhP[i] + c * 32), hf, ac[i]);
          }
        done |= ready;
      } while (done != 0xFFFFu);
    }

    // ---- LSTM update fully in-register; two 8B h publications (sc0 in
    // FAST: commit into the shared XCD L2, fire-and-forget).
    #pragma unroll
    for (int half = 0; half < 2; ++half) {
      u16 hv[4];
      #pragma unroll
      for (int r = 0; r < 4; ++r) {
        float ig = sigm  (ac[0*2+half][r] + bs[0*2+half][r]);
        float fg = sigm  (ac[1*2+half][r] + bs[1*2+half][r]);
        float gg = tanh_f(ac[2*2+half][r] + bs[2*2+half][r]);
        float og = sigm  (ac[3*2+half][r] + bs[3*2+half][r]);
        cc[half][r] = fg * cc[half][r] + ig * gg;
        hv[r] = f2bf(og * tanh_f(cc[half][r]));
      }
      v2u qv;
      qv[0] = (unsigned)hv[0] | ((unsigned)hv[1] << 16);
      qv[1] = (unsigned)hv[2] | ((unsigned)hv[3] << 16);
      u16* hp = h_buf + (size_t)((t + 1) & 3) * (Bb * Hh) + bat * Hh
              + j0 + half * 16 + q * 4;
      if constexpr (FAST)
        asm volatile("global_store_dwordx2 %0, %1, off sc0"
                     :: "v"(hp), "v"(qv) : "memory");
      else
        asm volatile("global_store_dwordx2 %0, %1, off sc0 sc1"
                     :: "v"(hp), "v"(qv) : "memory");
    }

    // ---- re-sentinel own produced region of the now-dead slot (t-1)&3.
    // Safe: this step's consume proves all group agents finished reading
    // slot (t-1)&3; per-address same-wave store order (clear @ t, next h
    // @ t+2) keeps L2 in order; an early-visible clear = consumer retry.
    if (t > 0) {
      #pragma unroll
      for (int half = 0; half < 2; ++half) {
        u16* cp = h_buf + (size_t)((t - 1) & 3) * (Bb * Hh) + bat * Hh
                + j0 + half * 16 + q * 4;
        v2u sv; sv[0] = SENT; sv[1] = SENT;
        if constexpr (FAST)
          asm volatile("global_store_dwordx2 %0, %1, off sc0"
                       :: "v"(cp), "v"(sv) : "memory");
        else
          asm volatile("global_store_dwordx2 %0, %1, off sc0 sc1"
                       :: "v"(cp), "v"(sv) : "memory");
      }
    }
  }
}

__global__ __launch_bounds__(64, 1) void lstm_main(
    const float* __restrict__ whh_mu, const float* __restrict__ whh_rho, const float* __restrict__ whh_eps,
    const float* __restrict__ wih_mu, const float* __restrict__ wih_rho, const float* __restrict__ wih_eps,
    const float* __restrict__ b_mu,  const float* __restrict__ b_rho,  const float* __restrict__ b_eps,
    const u16* __restrict__ x_bf, u16* __restrict__ h_buf)
{
  extern __shared__ char smem[];
  u16* w_hh_lds = (u16*)smem;                 // [NCOL][WHH_S]
  u16* w_ih_lds = w_hh_lds + NCOL * WHH_S;    // [NCOL][WIH_S]

  const int tid = threadIdx.x;
  // XCD-coherent mapping (round-robin dispatch XCD=blockIdx%8, verified
  // at runtime): all 16 blocks of group g share blockIdx&15 -> one XCD.
  const int jrow  = blockIdx.x & 15;
  const int g     = ((jrow & 7) << 1) | (jrow >> 3);
  const int chunk = blockIdx.x >> 4;
  const int b0    = g * BT;
  const int j0    = chunk * HC;

  unsigned* xcd_arr = (unsigned*)(h_buf + 4 * Bb * Hh);   // 256 entries

  // ---- publish own XCD (system scope) for the group handshake
  unsigned myx;
  asm volatile("s_getreg_b32 %0, hwreg(HW_REG_XCC_ID)" : "=s"(myx));
  myx &= 0xffu;
  unsigned mv = 0x100u | myx;
  if (tid == 0) {
    unsigned* xp = xcd_arr + blockIdx.x;
    asm volatile("global_store_dword %0, %1, off sc0 sc1"
                 :: "v"(xp), "v"(mv) : "memory");
  }

  // ---- sample weight chunk into LDS: two columns per thread (128 cols)
  for (int lc = tid; lc < NCOL; lc += 64) {
    const int gcol = (lc >> 5) * Hh + j0 + (lc & 31);  // global gate column
    #pragma unroll 4
    for (int k = 0; k < Hh; ++k) {
      int gi = k * G4 + gcol;
      float w = whh_mu[gi] + softplus_f(whh_rho[gi]) * whh_eps[gi];
      w_hh_lds[lc * WHH_S + k] = f2bf(w);
    }
    #pragma unroll 4
    for (int k = 0; k < Dd; ++k) {
      int gi = k * G4 + gcol;
      float w = wih_mu[gi] + softplus_f(wih_rho[gi]) * wih_eps[gi];
      w_ih_lds[lc * WIH_S + k] = f2bf(w);
    }
  }

  // ---- geometry: ONE wave owns the full chunk.
  // tile i covers LDS rows (i*16 + ln): gate = i>>1, hidden half = i&1;
  // lane: ln = batch col, q = k-quarter (ko = q*8).
  const int lane = tid & 63;
  const int ln   = lane & 15;
  const int q    = lane >> 4;
  const int ko   = q * 8;

  const u16* WhP[8]; const u16* WxP[8];
  #pragma unroll
  for (int i = 0; i < 8; ++i) {
    WhP[i] = w_hh_lds + (i * 16 + ln) * WHH_S + ko;
    WxP[i] = w_ih_lds + (i * 16 + ln) * WIH_S + ko;
  }

  const int bat = b0 + ln;   // this lane's batch row (B-operand col)

  // ---- per-lane biases: tile i=gt*2+half -> hidden half*16 + q*4 + r
  float bs[8][4];
  #pragma unroll
  for (int gt = 0; gt < 4; ++gt)
    #pragma unroll
    for (int half = 0; half < 2; ++half)
      #pragma unroll
      for (int r = 0; r < 4; ++r) {
        int colg = gt * Hh + j0 + half * 16 + q * 4 + r;
        bs[gt * 2 + half][r] = b_mu[colg] + softplus_f(b_rho[colg]) * b_eps[colg];
      }

  // ---- group XCD-uniformity handshake (one-time, system scope).
  int fast;
  {
    const unsigned* xp = xcd_arr + (lane & 15) * 16 + jrow;
    for (;;) {
      unsigned v;
      asm volatile("global_load_dword %0, %1, off sc0 sc1"
                   : "=v"(v) : "v"(xp));
      asm volatile("s_waitcnt vmcnt(0)");
      asm volatile("" : "+v"(v));
      if (__all((int)(v != SENT))) {
        fast = __all((int)(v == mv));
        break;
      }
    }
  }

  __syncthreads();   // LDS writes visible (one-time)

  if (fast)
    run_steps<true >(WhP, WxP, bs, x_bf, h_buf, bat, j0, q, ko);
  else
    run_steps<false>(WhP, WxP, bs, x_bf, h_buf, bat, j0, q, ko);
}

// ---------------------------------------------------------------- epilogue:
// out[b] = h_last[b,:] . lin_w + lin_b
// h(512) lives in slot (511+1)&3 = 0 -> h_buf base.
// Dispatch-boundary release writes back the per-XCD L2s (R12/R16-verified).
__global__ void k_out(const u16* __restrict__ h, const float* __restrict__ lw,
                      const float* __restrict__ lb, float* __restrict__ out)
{
  int b = blockIdx.x * 64 + threadIdx.x;
  if (b >= Bb) return;
  const u16* hr = h + b * Hh;
  float acc = 0.f;
  #pragma unroll 8
  for (int k = 0; k < Hh; ++k) acc += bf2f(hr[k]) * lw[k];
  out[b] = acc + lb[0];
}

extern "C" void kernel_launch(void* const* d_in, const int* in_sizes, int n_in,
                              void* d_out, int out_size, void* d_ws, size_t ws_size,
                              hipStream_t stream)
{
  (void)in_sizes; (void)n_in; (void)out_size; (void)ws_size;
  const float* x       = (const float*)d_in[0];
  const float* wih_mu  = (const float*)d_in[1];
  const float* wih_rho = (const float*)d_in[2];
  const float* wih_eps = (const float*)d_in[3];
  const float* whh_mu  = (const float*)d_in[4];
  const float* whh_rho = (const float*)d_in[5];
  const float* whh_eps = (const float*)d_in[6];
  const float* b_mu    = (const float*)d_in[7];
  const float* b_rho   = (const float*)d_in[8];
  const float* b_eps   = (const float*)d_in[9];
  const float* lin_w   = (const float*)d_in[10];
  const float* lin_b   = (const float*)d_in[11];
  float* out = (float*)d_out;

  // workspace layout
  u16* x_bf  = (u16*)d_ws;                       // T*B*D bf16  = 16 MB
  u16* h_buf = x_bf + (size_t)Tt * Bb * Dd;      // 4 ring slots (1 MB)
                                                 // + 256 u32 xcd table

  k_prep<<<2048, 256, 0, stream>>>(x, x_bf, h_buf);

  hipFuncSetAttribute(reinterpret_cast<const void*>(lstm_main),
                      hipFuncAttributeMaxDynamicSharedMemorySize, SMEM_BYTES);
  lstm_main<<<NGROUP * NCHUNK, 64, SMEM_BYTES, stream>>>(
      whh_mu, whh_rho, whh_eps, wih_mu, wih_rho, wih_eps,
      b_mu, b_rho, b_eps, x_bf, h_buf);

  k_out<<<(Bb + 63) / 64, 64, 0, stream>>>(h_buf, lin_w, lin_b, out);
}